// Round 3
// baseline (217.745 us; speedup 1.0000x reference)
//
#include <hip/hip_runtime.h>
#include <hip/hip_bf16.h>
#include <cstdint>
#include <cstddef>

#define N_TOK 65536
#define DIM 128
#define HID 256
#define NE 32
#define TOPK 2

typedef __bf16 bf16x8 __attribute__((ext_vector_type(8)));
typedef float f32x4 __attribute__((ext_vector_type(4)));
typedef unsigned uint4v __attribute__((ext_vector_type(4)));

// LDS address with XOR swizzle: inject c's low 2 bits into bank bits 5-6.
// Spreads the 8-bank clustering of the GEMM1 b64 epilogue writes and the
// quad-invariant read groups. Applied uniformly to every xa/ha access.
#define LDSA(c, row, byte) ((((c) * 1024 + (row) * 16 + (byte))) ^ ((((c) & 3) << 5)))

__device__ __forceinline__ unsigned short f2bf(float f) {
  unsigned u = __builtin_bit_cast(unsigned, f);
  u += 0x7fffu + ((u >> 16) & 1u);   // round-to-nearest-even
  return (unsigned short)(u >> 16);
}
__device__ __forceinline__ float bf2f(unsigned s) {
  return __builtin_bit_cast(float, s << 16);
}
// truncation split: f = hi + lo + O(2^-14 |f|); packs two values' shorts into one uint.
__device__ __forceinline__ uint2 split2(float f0, float f1) {
  unsigned u0 = __builtin_bit_cast(unsigned, f0);
  unsigned u1 = __builtin_bit_cast(unsigned, f1);
  unsigned hi = (u0 >> 16) | (u1 & 0xffff0000u);
  float r0 = f0 - __builtin_bit_cast(float, u0 & 0xffff0000u);
  float r1 = f1 - __builtin_bit_cast(float, u1 & 0xffff0000u);
  unsigned lo = (__builtin_bit_cast(unsigned, r0) >> 16) |
                (__builtin_bit_cast(unsigned, r1) & 0xffff0000u);
  uint2 ret; ret.x = hi; ret.y = lo;
  return ret;
}

// ---------------- fallback-only: zero out ----------------
__global__ void k_zero_out(float* __restrict__ out) {
  int t = blockIdx.x * 256 + threadIdx.x;
  float4 z = make_float4(0.f, 0.f, 0.f, 0.f);
  float4* o4 = (float4*)out;
  o4[t] = z;
  o4[t + 1048576] = z;
}

// ---------------- k_front: router (+inline fp64 fix, hist, xb) + weight transpose ----------------
// blocks 0..511:    router, 128 tokens each. Builds Wr MFMA fragments directly from Wr.
//                   Writes top_idx/top_val, xb (bf16 x), histbuf[b][32], impbuf[b][32].
// blocks 512..1023: W1/W2 bf16 transpose with fragment-col remap:
//   w1t fragment col (jt,l15) within 64-group <-> actual h = base + 4*l15 + jt
//   w2t fragment col (jt,l15) within 32-group <-> actual d = base + 2*l15 + jt
__global__ __launch_bounds__(256, 2) void k_front(
    const float* __restrict__ x, const float* __restrict__ W1,
    const float* __restrict__ W2, const float* __restrict__ Wr,
    const float* __restrict__ br,
    int* __restrict__ top_idx, float* __restrict__ top_val,
    unsigned short* __restrict__ xb,
    unsigned short* __restrict__ w1t, unsigned short* __restrict__ w2t,
    int* __restrict__ histbuf, float* __restrict__ impbuf) {
  int b = blockIdx.x;
  int t = threadIdx.x;

  if (b >= 512) {
    // ---------- weight transpose ----------
    int bb = b - 512;
    const float* in;
    unsigned short* outp;
    int K, r0, c0;
    bool isW1;
    if (bb < 256) {
      int e = bb >> 3, tt = bb & 7;
      in = W1 + (size_t)e * DIM * HID;   // [d][h] 128x256
      outp = w1t + (size_t)e * DIM * HID;
      K = HID;
      r0 = (tt >> 2) * 64; c0 = (tt & 3) * 64;
      isW1 = true;
    } else {
      bb -= 256;
      int e = bb >> 3, tt = bb & 7;
      in = W2 + (size_t)e * HID * DIM;   // [h][d] 256x128
      outp = w2t + (size_t)e * HID * DIM;
      K = DIM;
      r0 = (tt >> 1) * 64; c0 = (tt & 1) * 64;
      isW1 = false;
    }
    __shared__ float tile[64][65];
    int r = t >> 2, cs = (t & 3) * 16;
    const float* src = in + (size_t)(r0 + r) * K + c0 + cs;
#pragma unroll
    for (int j = 0; j < 4; ++j) {
      float4 v = *(const float4*)(src + j * 4);
      tile[r][cs + j * 4 + 0] = v.x;
      tile[r][cs + j * 4 + 1] = v.y;
      tile[r][cs + j * 4 + 2] = v.z;
      tile[r][cs + j * 4 + 3] = v.w;
    }
    __syncthreads();
#pragma unroll
    for (int p = 0; p < 2; ++p) {
      int orow = p * 32 + (t >> 3);
      int oc8 = (t & 7) * 8;
      int rr = r0 + oc8;
      unsigned pk[4];
#pragma unroll
      for (int q = 0; q < 4; ++q) {
        unsigned lo = f2bf(tile[oc8 + 2 * q][orow]);
        unsigned hi = f2bf(tile[oc8 + 2 * q + 1][orow]);
        pk[q] = lo | (hi << 16);
      }
      uint4 u;
      u.x = pk[0]; u.y = pk[1]; u.z = pk[2]; u.w = pk[3];
      int h = c0 + orow;
      int hp = isW1 ? ((h & ~63) | ((h & 3) << 4) | ((h & 63) >> 2))
                    : ((h & ~31) | ((h & 1) << 4) | ((h & 31) >> 1));
      size_t addr = (size_t)(rr >> 5) * (K * 32) + (size_t)hp * 32 + (rr & 31);
      *(uint4*)(outp + addr) = u;
    }
    return;
  }

  // ---------- router ----------
  __shared__ int hc[NE];
  __shared__ float hf[NE];
  __shared__ int slist[128];
  __shared__ int scount;
  if (t < NE) { hc[t] = 0; hf[t] = 0.f; }
  if (t == 0) scount = 0;
  __syncthreads();

  int w = t >> 6, l = t & 63, quad = l >> 4, l15 = l & 15;
  int tok0 = b * 128 + w * 32;

  // Build B fragments (hi/lo split) directly from Wr (L1/L2-hot 16 KB table)
  bf16x8 bfr[2][2][4];
#pragma unroll
  for (int nt = 0; nt < 2; ++nt)
#pragma unroll
    for (int kc = 0; kc < 4; ++kc) {
      unsigned hiw[4], low[4];
#pragma unroll
      for (int jp = 0; jp < 4; ++jp) {
        int k0 = kc * 32 + quad * 8 + jp * 2;
        int e = nt * 16 + l15;
        float w0 = Wr[k0 * NE + e];
        float w1v = Wr[(k0 + 1) * NE + e];
        uint2 s = split2(w0, w1v);
        hiw[jp] = s.x; low[jp] = s.y;
      }
      uint4v h4, l4;
      h4[0] = hiw[0]; h4[1] = hiw[1]; h4[2] = hiw[2]; h4[3] = hiw[3];
      l4[0] = low[0]; l4[1] = low[1]; l4[2] = low[2]; l4[3] = low[3];
      bfr[0][nt][kc] = __builtin_bit_cast(bf16x8, h4);
      bfr[1][nt][kc] = __builtin_bit_cast(bf16x8, l4);
    }

  f32x4 acc[2][2];
#pragma unroll
  for (int a = 0; a < 2; ++a)
#pragma unroll
    for (int bb = 0; bb < 2; ++bb) {
      f32x4 z = {0.f, 0.f, 0.f, 0.f};
      acc[a][bb] = z;
    }

#pragma unroll
  for (int mt = 0; mt < 2; ++mt) {
    const float* xp = x + (size_t)(tok0 + mt * 16 + l15) * DIM + quad * 8;
    float4 va[4][2];
#pragma unroll
    for (int kc = 0; kc < 4; ++kc) {
      const float4* p = (const float4*)(xp + kc * 32);
      va[kc][0] = p[0];
      va[kc][1] = p[1];
    }
    // bf16 row-major copy of x for k_expert's gather
    unsigned short* xrow = xb + (size_t)(tok0 + mt * 16 + l15) * DIM + quad * 8;
#pragma unroll
    for (int kc = 0; kc < 4; ++kc) {
      uint4 u;
      u.x = (unsigned)f2bf(va[kc][0].x) | ((unsigned)f2bf(va[kc][0].y) << 16);
      u.y = (unsigned)f2bf(va[kc][0].z) | ((unsigned)f2bf(va[kc][0].w) << 16);
      u.z = (unsigned)f2bf(va[kc][1].x) | ((unsigned)f2bf(va[kc][1].y) << 16);
      u.w = (unsigned)f2bf(va[kc][1].z) | ((unsigned)f2bf(va[kc][1].w) << 16);
      *(uint4*)(xrow + kc * 32) = u;
    }
#pragma unroll
    for (int kc = 0; kc < 4; ++kc) {
      uint2 s0 = split2(va[kc][0].x, va[kc][0].y);
      uint2 s1 = split2(va[kc][0].z, va[kc][0].w);
      uint2 s2 = split2(va[kc][1].x, va[kc][1].y);
      uint2 s3 = split2(va[kc][1].z, va[kc][1].w);
      uint4v hu, lu;
      hu[0] = s0.x; lu[0] = s0.y;
      hu[1] = s1.x; lu[1] = s1.y;
      hu[2] = s2.x; lu[2] = s2.y;
      hu[3] = s3.x; lu[3] = s3.y;
      bf16x8 ahi = __builtin_bit_cast(bf16x8, hu);
      bf16x8 alo = __builtin_bit_cast(bf16x8, lu);
#pragma unroll
      for (int nt = 0; nt < 2; ++nt) {
        acc[mt][nt] = __builtin_amdgcn_mfma_f32_16x16x32_bf16(ahi, bfr[0][nt][kc], acc[mt][nt], 0, 0, 0);
        acc[mt][nt] = __builtin_amdgcn_mfma_f32_16x16x32_bf16(ahi, bfr[1][nt][kc], acc[mt][nt], 0, 0, 0);
        acc[mt][nt] = __builtin_amdgcn_mfma_f32_16x16x32_bf16(alo, bfr[0][nt][kc], acc[mt][nt], 0, 0, 0);
      }
    }
  }

  float brv0 = br[l15], brv1 = br[16 + l15];
  const float NINF = -3.0e38f;
#pragma unroll
  for (int mt = 0; mt < 2; ++mt) {
#pragma unroll
    for (int r = 0; r < 4; ++r) {
      float c0 = acc[mt][0][r] + brv0;
      float c1 = acc[mt][1][r] + brv1;
      // pass 1: max with lowest-index tiebreak
      float va = (c0 >= c1) ? c0 : c1;
      int ia = (c0 >= c1) ? l15 : 16 + l15;
#pragma unroll
      for (int off = 1; off < 16; off <<= 1) {
        float ov = __shfl_xor(va, off);
        int oi = __shfl_xor(ia, off);
        if (ov > va || (ov == va && oi < ia)) { va = ov; ia = oi; }
      }
      float v1 = va; int i1 = ia;
      // pass 2
      float d0 = (i1 == l15) ? NINF : c0;
      float d1 = (i1 == 16 + l15) ? NINF : c1;
      float vb = (d0 >= d1) ? d0 : d1;
      int ib = (d0 >= d1) ? l15 : 16 + l15;
#pragma unroll
      for (int off = 1; off < 16; off <<= 1) {
        float ov = __shfl_xor(vb, off);
        int oi = __shfl_xor(ib, off);
        if (ov > vb || (ov == vb && oi < ib)) { vb = ov; ib = oi; }
      }
      float v2 = vb; int i2 = ib;
      // pass 3: third-largest (suspect detection)
      float e0 = (i1 == l15 || i2 == l15) ? NINF : c0;
      float e1 = (i1 == 16 + l15 || i2 == 16 + l15) ? NINF : c1;
      float vc = (e0 >= e1) ? e0 : e1;
#pragma unroll
      for (int off = 1; off < 16; off <<= 1) {
        float ov = __shfl_xor(vc, off);
        vc = (ov > vc) ? ov : vc;
      }
      // softmax denominator
      float s = __expf(c0 - v1) + __expf(c1 - v1);
#pragma unroll
      for (int off = 1; off < 16; off <<= 1) s += __shfl_xor(s, off);
      if (l15 == 0) {
        int n = tok0 + mt * 16 + quad * 4 + r;
        int2 ti; ti.x = i1; ti.y = i2;
        float2 tv; tv.x = 1.0f / s; tv.y = __expf(v2 - v1) / s;
        ((int2*)top_idx)[n] = ti;
        ((float2*)top_val)[n] = tv;
        atomicAdd(&hc[i1], 1);
        atomicAdd(&hc[i2], 1);
        atomicAdd(&hf[i1], tv.x);
        atomicAdd(&hf[i2], tv.y);
        if (v2 - vc < 2e-3f) {
          int si = atomicAdd(&scount, 1);
          if (si < 128) slist[si] = n;
        }
      }
    }
  }
  __syncthreads();

  // ---------- inline fp64 re-resolution of this block's near-tie tokens ----------
  int sc = scount;
  for (int s = (t >> 5); s < sc; s += 8) {
    int lt = t & 31;
    int n = slist[s];
    const float* xr = x + (size_t)n * DIM;
    double a = 0.0;
#pragma unroll 8
    for (int d = 0; d < DIM; ++d) a = fma((double)xr[d], (double)Wr[d * NE + lt], a);
    double lv = a + (double)br[lt];

    double v1 = lv; int i1 = lt;
#pragma unroll
    for (int off = 16; off > 0; off >>= 1) {
      double ov = __shfl_xor(v1, off, 32);
      int oi = __shfl_xor(i1, off, 32);
      if (ov > v1 || (ov == v1 && oi < i1)) { v1 = ov; i1 = oi; }
    }
    double lv2 = (lt == i1) ? -1.0e300 : lv;
    double v2 = lv2; int i2 = lt;
#pragma unroll
    for (int off = 16; off > 0; off >>= 1) {
      double ov = __shfl_xor(v2, off, 32);
      int oi = __shfl_xor(i2, off, 32);
      if (ov > v2 || (ov == v2 && oi < i2)) { v2 = ov; i2 = oi; }
    }
    float p = expf((float)(lv - v1));
    float ssum = p;
#pragma unroll
    for (int off = 16; off > 0; off >>= 1) ssum += __shfl_xor(ssum, off, 32);
    if (lt == 0) {
      int o1 = top_idx[n * 2 + 0];
      int o2 = top_idx[n * 2 + 1];
      float w1v = top_val[n * 2 + 0];
      float w2v = top_val[n * 2 + 1];
      float nv1 = 1.0f / ssum;
      float nv2 = expf((float)(v2 - v1)) / ssum;
      atomicAdd(&hc[o1], -1); atomicAdd(&hc[o2], -1);
      atomicAdd(&hc[i1], 1);  atomicAdd(&hc[i2], 1);
      atomicAdd(&hf[o1], -w1v); atomicAdd(&hf[o2], -w2v);
      atomicAdd(&hf[i1], nv1);  atomicAdd(&hf[i2], nv2);
      top_idx[n * 2 + 0] = i1;
      top_idx[n * 2 + 1] = i2;
      top_val[n * 2 + 0] = nv1;
      top_val[n * 2 + 1] = nv2;
    }
  }
  __syncthreads();
  if (t < NE) {
    histbuf[b * NE + t] = hc[t];
    impbuf[b * NE + t] = hf[t];
  }
}

// ---------------- k_scatter2: deterministic scatter + offsets/counts/loss ----------------
// perm[pos] = token*2 + slot  (encodes the combine slot: ybt row index)
__global__ __launch_bounds__(256) void k_scatter2(
    const int* __restrict__ top_idx, const float* __restrict__ top_val,
    const int* __restrict__ histbuf, const float* __restrict__ impbuf,
    int* __restrict__ perm, float* __restrict__ gatev,
    int* __restrict__ offsets, int* __restrict__ counts, float* __restrict__ out_loss) {
  __shared__ int pf[8][32], pb[8][32];
  __shared__ int offs[NE], pref[NE], h2[NE];
  int b = blockIdx.x, t = threadIdx.x;
  if (t < NE) h2[t] = 0;
  int g = t >> 5, e = t & 31;
  int sf = 0, sb = 0;
  for (int j = 0; j < 64; ++j) {
    int bb = g * 64 + j;
    int v = histbuf[bb * NE + e];
    sf += v;
    sb += (bb < b) ? v : 0;
  }
  pf[g][e] = sf;
  pb[g][e] = sb;
  __syncthreads();
  if (t < 32) {
    int T = 0, P = 0;
#pragma unroll
    for (int g2 = 0; g2 < 8; ++g2) { T += pf[g2][t]; P += pb[g2][t]; }
    int pc = (T + 63) & ~63;
    int scn = pc;
#pragma unroll
    for (int off = 1; off < 32; off <<= 1) {
      int ov = __shfl_up(scn, off, 32);
      if (t >= off) scn += ov;
    }
    offs[t] = scn - pc;
    pref[t] = P;
    if (b == 0) {
      offsets[t] = scn - pc;
      counts[t] = T;
      if (t == 31) offsets[NE] = scn;
    }
  }
  __syncthreads();
  if (t < 128) {
    int n = b * 128 + t;
    int2 ti = ((const int2*)top_idx)[n];
    float2 tv = ((const float2*)top_val)[n];
    int r0 = atomicAdd(&h2[ti.x], 1);
    int r1 = atomicAdd(&h2[ti.y], 1);
    int p0 = offs[ti.x] + pref[ti.x] + r0;
    int p1 = offs[ti.y] + pref[ti.y] + r1;
    perm[p0] = n * 2;
    gatev[p0] = tv.x;
    perm[p1] = n * 2 + 1;
    gatev[p1] = tv.y;
  }
  if (b == 0) {
    __shared__ float pfi[8][32];
    float s2 = 0.f;
    for (int j = 0; j < 64; ++j) s2 += impbuf[(g * 64 + j) * NE + e];
    pfi[g][e] = s2;
    __syncthreads();
    if (t < 32) {
      float imp = 0.f;
#pragma unroll
      for (int g2 = 0; g2 < 8; ++g2) imp += pfi[g2][t];
      float ssum = imp;
#pragma unroll
      for (int off = 16; off > 0; off >>= 1) ssum += __shfl_xor(ssum, off, 32);
      float mean = ssum / 32.0f;
      float dlt = imp - mean;
      float v = dlt * dlt;
#pragma unroll
      for (int off = 16; off > 0; off >>= 1) v += __shfl_xor(v, off, 32);
      if (t == 0) *out_loss = (v / 31.0f) / (mean * mean + 1e-9f);
    }
  }
}

// ---------------- fused expert GEMM: 64 tokens x 1 expert per block ----------------
// YB=1: bf16 gather from xb, token-addressed ybt output. YB=0 (fallback): fp32 gather, atomic out.
// 32 KB LDS (ha aliases xa), 4 blocks/CU. Fragment-col remap gives packed epilogues.
template <int YB>
__global__ __launch_bounds__(256, 4) void k_expert(
    const float* __restrict__ x, const unsigned short* __restrict__ xb,
    const unsigned short* __restrict__ w1t, const unsigned short* __restrict__ w2t,
    const float* __restrict__ b1, const float* __restrict__ b2,
    const int* __restrict__ offsets, const int* __restrict__ counts,
    const int* __restrict__ perm, const float* __restrict__ gatev,
    unsigned short* __restrict__ ybt, float* __restrict__ out) {
  __shared__ __align__(16) unsigned char smem[32768];   // xa: c 0..15; ha: c 0..31 (aliased)

  // XCD-affinity swizzle (2080 = 8*260, bijective)
  int bid = (int)(blockIdx.x & 7) * 260 + (int)(blockIdx.x >> 3);
  int slot0 = bid * 64;
  if (slot0 >= offsets[NE]) return;
  int e = 0;
#pragma unroll
  for (int i = 1; i < NE; ++i)
    if (slot0 >= offsets[i]) e = i;
  int cnt = counts[e];
  int local0 = slot0 - offsets[e];
  int nvalid = min(64, cnt - local0);

  int t = threadIdx.x;
  int w = t >> 6;
  int l = t & 63;
  int quad = l >> 4;
  int l15 = l & 15;

  int pvl = 0;
  float gvl = 0.f;
  if (YB) {
    uint4 v[4];
    if (l < nvalid) {
      pvl = perm[slot0 + l];
      gvl = gatev[slot0 + l];
      const uint4* rowp = (const uint4*)(xb + (size_t)(pvl >> 1) * DIM);
#pragma unroll
      for (int cc = 0; cc < 4; ++cc) v[cc] = rowp[w * 4 + cc];
    } else {
#pragma unroll
      for (int cc = 0; cc < 4; ++cc) { v[cc].x = 0u; v[cc].y = 0u; v[cc].z = 0u; v[cc].w = 0u; }
    }
#pragma unroll
    for (int cc = 0; cc < 4; ++cc)
      *(uint4*)(smem + LDSA(w * 4 + cc, l, 0)) = v[cc];
  } else {
    unsigned pk[16];
    if (l < nvalid) {
      pvl = perm[slot0 + l];
      gvl = gatev[slot0 + l];
      const float* src = x + (size_t)(pvl >> 1) * DIM + w * 32;
#pragma unroll
      for (int q = 0; q < 8; ++q) {
        float4 vv = ((const float4*)src)[q];
        pk[q * 2 + 0] = (unsigned)f2bf(vv.x) | ((unsigned)f2bf(vv.y) << 16);
        pk[q * 2 + 1] = (unsigned)f2bf(vv.z) | ((unsigned)f2bf(vv.w) << 16);
      }
    } else {
#pragma unroll
      for (int q = 0; q < 16; ++q) pk[q] = 0u;
    }
#pragma unroll
    for (int cc = 0; cc < 4; ++cc) {
      uint4 u;
      u.x = pk[cc * 4 + 0]; u.y = pk[cc * 4 + 1]; u.z = pk[cc * 4 + 2]; u.w = pk[cc * 4 + 3];
      *(uint4*)(smem + LDSA(w * 4 + cc, l, 0)) = u;
    }
  }

  const unsigned short* w1e = w1t + (size_t)e * DIM * HID;
  bf16x8 w1f[4][4];
#pragma unroll
  for (int kc = 0; kc < 4; ++kc)
#pragma unroll
    for (int jt = 0; jt < 4; ++jt)
      w1f[kc][jt] = *(const bf16x8*)(w1e + kc * 8192 + (w * 64 + jt * 16 + l15) * 32 + quad * 8);

  __syncthreads();   // (1) xa staged

  f32x4 acc[4][4];
#pragma unroll
  for (int a = 0; a < 4; ++a)
#pragma unroll
    for (int bb = 0; bb < 4; ++bb) {
      f32x4 z = {0.f, 0.f, 0.f, 0.f};
      acc[a][bb] = z;
    }
#pragma unroll
  for (int kc = 0; kc < 4; ++kc) {
    bf16x8 af[4];
#pragma unroll
    for (int rt = 0; rt < 4; ++rt)
      af[rt] = *(const bf16x8*)(smem + LDSA(kc * 4 + quad, rt * 16 + l15, 0));
#pragma unroll
    for (int rt = 0; rt < 4; ++rt)
#pragma unroll
      for (int jt = 0; jt < 4; ++jt)
        acc[rt][jt] = __builtin_amdgcn_mfma_f32_16x16x32_bf16(af[rt], w1f[kc][jt], acc[rt][jt], 0, 0, 0);
  }

  const unsigned short* w2e = w2t + (size_t)e * HID * DIM;
  bf16x8 w2f[8][2];
#pragma unroll
  for (int hc = 0; hc < 8; ++hc)
#pragma unroll
    for (int jt = 0; jt < 2; ++jt)
      w2f[hc][jt] = *(const bf16x8*)(w2e + hc * 4096 + (w * 32 + jt * 16 + l15) * 32 + quad * 8);

  __syncthreads();   // (2) all xa reads done; ha may overwrite

  // GEMM1 epilogue: lane's 4 jt-values are h = w*64 + 4*l15 + {0..3} (consecutive) -> one b64 write
  {
    float4 b1v = *(const float4*)(b1 + e * HID + w * 64 + 4 * l15);
    int c = w * 8 + (l15 >> 1);
    int byte = (l15 & 1) * 8;
#pragma unroll
    for (int rt = 0; rt < 4; ++rt) {
#pragma unroll
      for (int r = 0; r < 4; ++r) {
        int tokrow = rt * 16 + quad * 4 + r;
        float v0 = acc[rt][0][r] + b1v.x; v0 = v0 > 0.f ? v0 : 0.f;
        float v1 = acc[rt][1][r] + b1v.y; v1 = v1 > 0.f ? v1 : 0.f;
        float v2 = acc[rt][2][r] + b1v.z; v2 = v2 > 0.f ? v2 : 0.f;
        float v3 = acc[rt][3][r] + b1v.w; v3 = v3 > 0.f ? v3 : 0.f;
        uint2 u;
        u.x = (unsigned)f2bf(v0) | ((unsigned)f2bf(v1) << 16);
        u.y = (unsigned)f2bf(v2) | ((unsigned)f2bf(v3) << 16);
        *(uint2*)(smem + LDSA(c, tokrow, byte)) = u;
      }
    }
  }
  __syncthreads();   // (3) ha ready

  f32x4 accc[4][2];
#pragma unroll
  for (int a = 0; a < 4; ++a)
#pragma unroll
    for (int bb = 0; bb < 2; ++bb) {
      f32x4 z = {0.f, 0.f, 0.f, 0.f};
      accc[a][bb] = z;
    }
#pragma unroll
  for (int hc = 0; hc < 8; ++hc) {
    bf16x8 ah[4];
#pragma unroll
    for (int rt = 0; rt < 4; ++rt)
      ah[rt] = *(const bf16x8*)(smem + LDSA(hc * 4 + quad, rt * 16 + l15, 0));
#pragma unroll
    for (int rt = 0; rt < 4; ++rt)
#pragma unroll
      for (int jt = 0; jt < 2; ++jt)
        accc[rt][jt] = __builtin_amdgcn_mfma_f32_16x16x32_bf16(ah[rt], w2f[hc][jt], accc[rt][jt], 0, 0, 0);
  }

  // GEMM2 epilogue: lane's 2 jt-values are d = w*32 + 2*l15 + {0,1} -> one 4B store
  int dbase = w * 32;
  float2 b2v = *(const float2*)(b2 + e * DIM + dbase + 2 * l15);
#pragma unroll
  for (int rt = 0; rt < 4; ++rt) {
#pragma unroll
    for (int r = 0; r < 4; ++r) {
      int tokrow = rt * 16 + quad * 4 + r;
      int pv = __shfl(pvl, tokrow);     // all lanes participate
      float g = __shfl(gvl, tokrow);
      if (tokrow < nvalid) {
        float y0 = g * (accc[rt][0][r] + b2v.x);
        float y1 = g * (accc[rt][1][r] + b2v.y);
        if (YB) {
          unsigned pack = (unsigned)f2bf(y0) | ((unsigned)f2bf(y1) << 16);
          *(unsigned*)(ybt + (size_t)pv * DIM + dbase + 2 * l15) = pack;
        } else {
          float* orow = out + (size_t)(pv >> 1) * DIM + dbase + 2 * l15;
          atomicAdd(&orow[0], y0);
          atomicAdd(&orow[1], y1);
        }
      }
    }
  }
}

// ---------------- combine: out[n] = ybt[2n] + ybt[2n+1] (fully streaming) ----------------
__global__ __launch_bounds__(256) void k_combine(const unsigned short* __restrict__ ybt,
                                                 float* __restrict__ out) {
  int idx = blockIdx.x * 256 + threadIdx.x;
  int n = idx >> 4;
  int lane = idx & 15;
  uint4 a = *((const uint4*)(ybt + (size_t)(2 * n) * DIM) + lane);
  uint4 b = *((const uint4*)(ybt + (size_t)(2 * n + 1) * DIM) + lane);
  unsigned av[4] = {a.x, a.y, a.z, a.w}, bv[4] = {b.x, b.y, b.z, b.w};
  float r[8];
#pragma unroll
  for (int q = 0; q < 4; ++q) {
    r[q * 2 + 0] = bf2f(av[q] & 0xffffu) + bf2f(bv[q] & 0xffffu);
    r[q * 2 + 1] = bf2f(av[q] >> 16) + bf2f(bv[q] >> 16);
  }
  float* orow = out + (size_t)n * DIM + lane * 8;
  float4 w0 = {r[0], r[1], r[2], r[3]}, w1 = {r[4], r[5], r[6], r[7]};
  ((float4*)orow)[0] = w0;
  ((float4*)orow)[1] = w1;
}

extern "C" void kernel_launch(void* const* d_in, const int* in_sizes, int n_in,
                              void* d_out, int out_size, void* d_ws, size_t ws_size,
                              hipStream_t stream) {
  const float* x  = (const float*)d_in[0];
  const float* W1 = (const float*)d_in[1];
  const float* b1 = (const float*)d_in[2];
  const float* W2 = (const float*)d_in[3];
  const float* b2 = (const float*)d_in[4];
  const float* Wr = (const float*)d_in[5];
  const float* br = (const float*)d_in[6];
  float* out = (float*)d_out;

  char* ws = (char*)d_ws;
  int*   counts   = (int*)(ws + 0);        // 32 i
  int*   offsets  = (int*)(ws + 128);      // 33 i
  int*   top_idx  = (int*)(ws + 1024);     // 131072 i -> 525312
  float* top_val  = (float*)(ws + 525312); // 131072 f -> 1049600
  int*   perm     = (int*)(ws + 1049600);  // 133120 i -> 1582080
  float* gatev    = (float*)(ws + 1582080);// 133120 f -> 2114560
  int*   histbuf  = (int*)(ws + 2114560);  // 512*32 i -> 2180096
  float* impbuf   = (float*)(ws + 2180096);// 512*32 f -> 2245632
  unsigned short* w1t = (unsigned short*)(ws + 2638848); // 2 MB -> 4736000
  unsigned short* w2t = (unsigned short*)(ws + 4736000); // 2 MB -> 6833152
  unsigned short* ybt = (unsigned short*)(ws + 6833152); // 131072*128*2 = 33554432 -> 40387584
  const size_t NEEDED = 40387584;
  bool use_ybt = ws_size >= NEEDED;

  // bf16 copy of x in the head of `out` (16.8 MB): written by k_front's router
  // blocks, consumed by k_expert<1>, fully overwritten by k_combine afterwards.
  unsigned short* xb = (unsigned short*)out;

  if (use_ybt) {
    hipLaunchKernelGGL(k_front, dim3(1024), dim3(256), 0, stream, x, W1, W2, Wr, br,
                       top_idx, top_val, xb, w1t, w2t, histbuf, impbuf);
    hipLaunchKernelGGL(k_scatter2, dim3(512), dim3(256), 0, stream, top_idx, top_val,
                       histbuf, impbuf, perm, gatev, offsets, counts,
                       out + (size_t)N_TOK * DIM);
    hipLaunchKernelGGL((k_expert<1>), dim3(2080), dim3(256), 0, stream, x, xb, w1t, w2t,
                       b1, b2, offsets, counts, perm, gatev, ybt, out);
    hipLaunchKernelGGL(k_combine, dim3(4096), dim3(256), 0, stream, ybt, out);
  } else {
    hipLaunchKernelGGL(k_front, dim3(1024), dim3(256), 0, stream, x, W1, W2, Wr, br,
                       top_idx, top_val, xb, w1t, w2t, histbuf, impbuf);
    hipLaunchKernelGGL(k_scatter2, dim3(512), dim3(256), 0, stream, top_idx, top_val,
                       histbuf, impbuf, perm, gatev, offsets, counts,
                       out + (size_t)N_TOK * DIM);
    hipLaunchKernelGGL(k_zero_out, dim3(4096), dim3(256), 0, stream, out);
    hipLaunchKernelGGL((k_expert<0>), dim3(2080), dim3(256), 0, stream, x,
                       (const unsigned short*)0, w1t, w2t, b1, b2, offsets, counts,
                       perm, gatev, (unsigned short*)0, out);
  }
}

// Round 4
// 210.216 us; speedup vs baseline: 1.0358x; 1.0358x over previous
//
#include <hip/hip_runtime.h>
#include <hip/hip_bf16.h>
#include <cstdint>
#include <cstddef>

#define N_TOK 65536
#define DIM 128
#define HID 256
#define NE 32
#define TOPK 2

typedef __bf16 bf16x8 __attribute__((ext_vector_type(8)));
typedef float f32x4 __attribute__((ext_vector_type(4)));
typedef unsigned uint4v __attribute__((ext_vector_type(4)));

// LDS address with XOR swizzle: inject c's low 2 bits into bank bits 5-6.
#define LDSA(c, row, byte) ((((c) * 1024 + (row) * 16 + (byte))) ^ ((((c) & 3) << 5)))

__device__ __forceinline__ unsigned short f2bf(float f) {
  unsigned u = __builtin_bit_cast(unsigned, f);
  u += 0x7fffu + ((u >> 16) & 1u);   // round-to-nearest-even
  return (unsigned short)(u >> 16);
}
__device__ __forceinline__ float bf2f(unsigned s) {
  return __builtin_bit_cast(float, s << 16);
}
// truncation split: f = hi + lo + O(2^-14 |f|); packs two values' shorts into one uint.
__device__ __forceinline__ uint2 split2(float f0, float f1) {
  unsigned u0 = __builtin_bit_cast(unsigned, f0);
  unsigned u1 = __builtin_bit_cast(unsigned, f1);
  unsigned hi = (u0 >> 16) | (u1 & 0xffff0000u);
  float r0 = f0 - __builtin_bit_cast(float, u0 & 0xffff0000u);
  float r1 = f1 - __builtin_bit_cast(float, u1 & 0xffff0000u);
  unsigned lo = (__builtin_bit_cast(unsigned, r0) >> 16) |
                (__builtin_bit_cast(unsigned, r1) & 0xffff0000u);
  uint2 ret; ret.x = hi; ret.y = lo;
  return ret;
}

// ---------------- fallback-only: zero out ----------------
__global__ void k_zero_out(float* __restrict__ out) {
  int t = blockIdx.x * 256 + threadIdx.x;
  float4 z = make_float4(0.f, 0.f, 0.f, 0.f);
  float4* o4 = (float4*)out;
  o4[t] = z;
  o4[t + 1048576] = z;
}

// ---------------- k_front: router (+inline fp64 fix, hist, xb) + weight transpose ----------------
// blocks 0..511:    router, 128 tokens each. Builds Wr MFMA fragments directly from Wr.
// blocks 512..1023: W1/W2 bf16 transpose with fragment-col remap:
//   w1t fragment col (jt,l15) within 64-group <-> actual h = base + 4*l15 + jt
//   w2t fragment col (jt,l15) within 32-group <-> actual d = base + 2*l15 + jt
__global__ __launch_bounds__(256, 2) void k_front(
    const float* __restrict__ x, const float* __restrict__ W1,
    const float* __restrict__ W2, const float* __restrict__ Wr,
    const float* __restrict__ br,
    int* __restrict__ top_idx, float* __restrict__ top_val,
    unsigned short* __restrict__ xb,
    unsigned short* __restrict__ w1t, unsigned short* __restrict__ w2t,
    int* __restrict__ histbuf, float* __restrict__ impbuf) {
  int b = blockIdx.x;
  int t = threadIdx.x;

  if (b >= 512) {
    // ---------- weight transpose ----------
    int bb = b - 512;
    const float* in;
    unsigned short* outp;
    int K, r0, c0;
    bool isW1;
    if (bb < 256) {
      int e = bb >> 3, tt = bb & 7;
      in = W1 + (size_t)e * DIM * HID;   // [d][h] 128x256
      outp = w1t + (size_t)e * DIM * HID;
      K = HID;
      r0 = (tt >> 2) * 64; c0 = (tt & 3) * 64;
      isW1 = true;
    } else {
      bb -= 256;
      int e = bb >> 3, tt = bb & 7;
      in = W2 + (size_t)e * HID * DIM;   // [h][d] 256x128
      outp = w2t + (size_t)e * HID * DIM;
      K = DIM;
      r0 = (tt >> 1) * 64; c0 = (tt & 1) * 64;
      isW1 = false;
    }
    __shared__ float tile[64][65];
    int r = t >> 2, cs = (t & 3) * 16;
    const float* src = in + (size_t)(r0 + r) * K + c0 + cs;
#pragma unroll
    for (int j = 0; j < 4; ++j) {
      float4 v = *(const float4*)(src + j * 4);
      tile[r][cs + j * 4 + 0] = v.x;
      tile[r][cs + j * 4 + 1] = v.y;
      tile[r][cs + j * 4 + 2] = v.z;
      tile[r][cs + j * 4 + 3] = v.w;
    }
    __syncthreads();
#pragma unroll
    for (int p = 0; p < 2; ++p) {
      int orow = p * 32 + (t >> 3);
      int oc8 = (t & 7) * 8;
      int rr = r0 + oc8;
      unsigned pk[4];
#pragma unroll
      for (int q = 0; q < 4; ++q) {
        unsigned lo = f2bf(tile[oc8 + 2 * q][orow]);
        unsigned hi = f2bf(tile[oc8 + 2 * q + 1][orow]);
        pk[q] = lo | (hi << 16);
      }
      uint4 u;
      u.x = pk[0]; u.y = pk[1]; u.z = pk[2]; u.w = pk[3];
      int h = c0 + orow;
      int hp = isW1 ? ((h & ~63) | ((h & 3) << 4) | ((h & 63) >> 2))
                    : ((h & ~31) | ((h & 1) << 4) | ((h & 31) >> 1));
      size_t addr = (size_t)(rr >> 5) * (K * 32) + (size_t)hp * 32 + (rr & 31);
      *(uint4*)(outp + addr) = u;
    }
    return;
  }

  // ---------- router ----------
  __shared__ int hc[NE];
  __shared__ float hf[NE];
  __shared__ int slist[128];
  __shared__ int scount;
  if (t < NE) { hc[t] = 0; hf[t] = 0.f; }
  if (t == 0) scount = 0;
  __syncthreads();

  int w = t >> 6, l = t & 63, quad = l >> 4, l15 = l & 15;
  int tok0 = b * 128 + w * 32;

  // Build B fragments (hi/lo split) directly from Wr (L1/L2-hot 16 KB table)
  bf16x8 bfr[2][2][4];
#pragma unroll
  for (int nt = 0; nt < 2; ++nt)
#pragma unroll
    for (int kc = 0; kc < 4; ++kc) {
      unsigned hiw[4], low[4];
#pragma unroll
      for (int jp = 0; jp < 4; ++jp) {
        int k0 = kc * 32 + quad * 8 + jp * 2;
        int e = nt * 16 + l15;
        float w0 = Wr[k0 * NE + e];
        float w1v = Wr[(k0 + 1) * NE + e];
        uint2 s = split2(w0, w1v);
        hiw[jp] = s.x; low[jp] = s.y;
      }
      uint4v h4, l4;
      h4[0] = hiw[0]; h4[1] = hiw[1]; h4[2] = hiw[2]; h4[3] = hiw[3];
      l4[0] = low[0]; l4[1] = low[1]; l4[2] = low[2]; l4[3] = low[3];
      bfr[0][nt][kc] = __builtin_bit_cast(bf16x8, h4);
      bfr[1][nt][kc] = __builtin_bit_cast(bf16x8, l4);
    }

  f32x4 acc[2][2];
#pragma unroll
  for (int a = 0; a < 2; ++a)
#pragma unroll
    for (int bb = 0; bb < 2; ++bb) {
      f32x4 z = {0.f, 0.f, 0.f, 0.f};
      acc[a][bb] = z;
    }

#pragma unroll
  for (int mt = 0; mt < 2; ++mt) {
    const float* xp = x + (size_t)(tok0 + mt * 16 + l15) * DIM + quad * 8;
    float4 va[4][2];
#pragma unroll
    for (int kc = 0; kc < 4; ++kc) {
      const float4* p = (const float4*)(xp + kc * 32);
      va[kc][0] = p[0];
      va[kc][1] = p[1];
    }
    // bf16 row-major copy of x for k_expert's gather
    unsigned short* xrow = xb + (size_t)(tok0 + mt * 16 + l15) * DIM + quad * 8;
#pragma unroll
    for (int kc = 0; kc < 4; ++kc) {
      uint4 u;
      u.x = (unsigned)f2bf(va[kc][0].x) | ((unsigned)f2bf(va[kc][0].y) << 16);
      u.y = (unsigned)f2bf(va[kc][0].z) | ((unsigned)f2bf(va[kc][0].w) << 16);
      u.z = (unsigned)f2bf(va[kc][1].x) | ((unsigned)f2bf(va[kc][1].y) << 16);
      u.w = (unsigned)f2bf(va[kc][1].z) | ((unsigned)f2bf(va[kc][1].w) << 16);
      *(uint4*)(xrow + kc * 32) = u;
    }
#pragma unroll
    for (int kc = 0; kc < 4; ++kc) {
      uint2 s0 = split2(va[kc][0].x, va[kc][0].y);
      uint2 s1 = split2(va[kc][0].z, va[kc][0].w);
      uint2 s2 = split2(va[kc][1].x, va[kc][1].y);
      uint2 s3 = split2(va[kc][1].z, va[kc][1].w);
      uint4v hu, lu;
      hu[0] = s0.x; lu[0] = s0.y;
      hu[1] = s1.x; lu[1] = s1.y;
      hu[2] = s2.x; lu[2] = s2.y;
      hu[3] = s3.x; lu[3] = s3.y;
      bf16x8 ahi = __builtin_bit_cast(bf16x8, hu);
      bf16x8 alo = __builtin_bit_cast(bf16x8, lu);
#pragma unroll
      for (int nt = 0; nt < 2; ++nt) {
        acc[mt][nt] = __builtin_amdgcn_mfma_f32_16x16x32_bf16(ahi, bfr[0][nt][kc], acc[mt][nt], 0, 0, 0);
        acc[mt][nt] = __builtin_amdgcn_mfma_f32_16x16x32_bf16(ahi, bfr[1][nt][kc], acc[mt][nt], 0, 0, 0);
        acc[mt][nt] = __builtin_amdgcn_mfma_f32_16x16x32_bf16(alo, bfr[0][nt][kc], acc[mt][nt], 0, 0, 0);
      }
    }
  }

  float brv0 = br[l15], brv1 = br[16 + l15];
  const float NINF = -3.0e38f;
#pragma unroll
  for (int mt = 0; mt < 2; ++mt) {
#pragma unroll
    for (int r = 0; r < 4; ++r) {
      float c0 = acc[mt][0][r] + brv0;
      float c1 = acc[mt][1][r] + brv1;
      // pass 1: max with lowest-index tiebreak
      float va = (c0 >= c1) ? c0 : c1;
      int ia = (c0 >= c1) ? l15 : 16 + l15;
#pragma unroll
      for (int off = 1; off < 16; off <<= 1) {
        float ov = __shfl_xor(va, off);
        int oi = __shfl_xor(ia, off);
        if (ov > va || (ov == va && oi < ia)) { va = ov; ia = oi; }
      }
      float v1 = va; int i1 = ia;
      // pass 2
      float d0 = (i1 == l15) ? NINF : c0;
      float d1 = (i1 == 16 + l15) ? NINF : c1;
      float vb = (d0 >= d1) ? d0 : d1;
      int ib = (d0 >= d1) ? l15 : 16 + l15;
#pragma unroll
      for (int off = 1; off < 16; off <<= 1) {
        float ov = __shfl_xor(vb, off);
        int oi = __shfl_xor(ib, off);
        if (ov > vb || (ov == vb && oi < ib)) { vb = ov; ib = oi; }
      }
      float v2 = vb; int i2 = ib;
      // pass 3: third-largest (suspect detection)
      float e0 = (i1 == l15 || i2 == l15) ? NINF : c0;
      float e1 = (i1 == 16 + l15 || i2 == 16 + l15) ? NINF : c1;
      float vc = (e0 >= e1) ? e0 : e1;
#pragma unroll
      for (int off = 1; off < 16; off <<= 1) {
        float ov = __shfl_xor(vc, off);
        vc = (ov > vc) ? ov : vc;
      }
      // softmax denominator
      float s = __expf(c0 - v1) + __expf(c1 - v1);
#pragma unroll
      for (int off = 1; off < 16; off <<= 1) s += __shfl_xor(s, off);
      if (l15 == 0) {
        int n = tok0 + mt * 16 + quad * 4 + r;
        int2 ti; ti.x = i1; ti.y = i2;
        float2 tv; tv.x = 1.0f / s; tv.y = __expf(v2 - v1) / s;
        ((int2*)top_idx)[n] = ti;
        ((float2*)top_val)[n] = tv;
        atomicAdd(&hc[i1], 1);
        atomicAdd(&hc[i2], 1);
        atomicAdd(&hf[i1], tv.x);
        atomicAdd(&hf[i2], tv.y);
        if (v2 - vc < 2e-3f) {
          int si = atomicAdd(&scount, 1);
          if (si < 128) slist[si] = n;
        }
      }
    }
  }
  __syncthreads();

  // ---------- inline fp64 re-resolution of this block's near-tie tokens ----------
  int sc = scount;
  for (int s = (t >> 5); s < sc; s += 8) {
    int lt = t & 31;
    int n = slist[s];
    const float* xr = x + (size_t)n * DIM;
    double a = 0.0;
#pragma unroll 8
    for (int d = 0; d < DIM; ++d) a = fma((double)xr[d], (double)Wr[d * NE + lt], a);
    double lv = a + (double)br[lt];

    double v1 = lv; int i1 = lt;
#pragma unroll
    for (int off = 16; off > 0; off >>= 1) {
      double ov = __shfl_xor(v1, off, 32);
      int oi = __shfl_xor(i1, off, 32);
      if (ov > v1 || (ov == v1 && oi < i1)) { v1 = ov; i1 = oi; }
    }
    double lv2 = (lt == i1) ? -1.0e300 : lv;
    double v2 = lv2; int i2 = lt;
#pragma unroll
    for (int off = 16; off > 0; off >>= 1) {
      double ov = __shfl_xor(v2, off, 32);
      int oi = __shfl_xor(i2, off, 32);
      if (ov > v2 || (ov == v2 && oi < i2)) { v2 = ov; i2 = oi; }
    }
    float p = expf((float)(lv - v1));
    float ssum = p;
#pragma unroll
    for (int off = 16; off > 0; off >>= 1) ssum += __shfl_xor(ssum, off, 32);
    if (lt == 0) {
      int o1 = top_idx[n * 2 + 0];
      int o2 = top_idx[n * 2 + 1];
      float w1v = top_val[n * 2 + 0];
      float w2v = top_val[n * 2 + 1];
      float nv1 = 1.0f / ssum;
      float nv2 = expf((float)(v2 - v1)) / ssum;
      atomicAdd(&hc[o1], -1); atomicAdd(&hc[o2], -1);
      atomicAdd(&hc[i1], 1);  atomicAdd(&hc[i2], 1);
      atomicAdd(&hf[o1], -w1v); atomicAdd(&hf[o2], -w2v);
      atomicAdd(&hf[i1], nv1);  atomicAdd(&hf[i2], nv2);
      top_idx[n * 2 + 0] = i1;
      top_idx[n * 2 + 1] = i2;
      top_val[n * 2 + 0] = nv1;
      top_val[n * 2 + 1] = nv2;
    }
  }
  __syncthreads();
  if (t < NE) {
    histbuf[b * NE + t] = hc[t];
    impbuf[b * NE + t] = hf[t];
  }
}

// ---------------- k_scatter2: deterministic scatter + offsets/counts/loss + inv map ----------------
// perm[pos] = token; inv[token*2+slot] = pos (for combine's gather)
__global__ __launch_bounds__(256) void k_scatter2(
    const int* __restrict__ top_idx, const float* __restrict__ top_val,
    const int* __restrict__ histbuf, const float* __restrict__ impbuf,
    int* __restrict__ perm, float* __restrict__ gatev, int* __restrict__ inv,
    int* __restrict__ offsets, int* __restrict__ counts, float* __restrict__ out_loss) {
  __shared__ int pf[8][32], pb[8][32];
  __shared__ int offs[NE], pref[NE], h2[NE];
  int b = blockIdx.x, t = threadIdx.x;
  if (t < NE) h2[t] = 0;
  int g = t >> 5, e = t & 31;
  int sf = 0, sb = 0;
  for (int j = 0; j < 64; ++j) {
    int bb = g * 64 + j;
    int v = histbuf[bb * NE + e];
    sf += v;
    sb += (bb < b) ? v : 0;
  }
  pf[g][e] = sf;
  pb[g][e] = sb;
  __syncthreads();
  if (t < 32) {
    int T = 0, P = 0;
#pragma unroll
    for (int g2 = 0; g2 < 8; ++g2) { T += pf[g2][t]; P += pb[g2][t]; }
    int pc = (T + 63) & ~63;
    int scn = pc;
#pragma unroll
    for (int off = 1; off < 32; off <<= 1) {
      int ov = __shfl_up(scn, off, 32);
      if (t >= off) scn += ov;
    }
    offs[t] = scn - pc;
    pref[t] = P;
    if (b == 0) {
      offsets[t] = scn - pc;
      counts[t] = T;
      if (t == 31) offsets[NE] = scn;
    }
  }
  __syncthreads();
  if (t < 128) {
    int n = b * 128 + t;
    int2 ti = ((const int2*)top_idx)[n];
    float2 tv = ((const float2*)top_val)[n];
    int r0 = atomicAdd(&h2[ti.x], 1);
    int r1 = atomicAdd(&h2[ti.y], 1);
    int p0 = offs[ti.x] + pref[ti.x] + r0;
    int p1 = offs[ti.y] + pref[ti.y] + r1;
    perm[p0] = n;
    gatev[p0] = tv.x;
    perm[p1] = n;
    gatev[p1] = tv.y;
    int2 iv; iv.x = p0; iv.y = p1;
    ((int2*)inv)[n] = iv;
  }
  if (b == 0) {
    __shared__ float pfi[8][32];
    float s2 = 0.f;
    for (int j = 0; j < 64; ++j) s2 += impbuf[(g * 64 + j) * NE + e];
    pfi[g][e] = s2;
    __syncthreads();
    if (t < 32) {
      float imp = 0.f;
#pragma unroll
      for (int g2 = 0; g2 < 8; ++g2) imp += pfi[g2][t];
      float ssum = imp;
#pragma unroll
      for (int off = 16; off > 0; off >>= 1) ssum += __shfl_xor(ssum, off, 32);
      float mean = ssum / 32.0f;
      float dlt = imp - mean;
      float v = dlt * dlt;
#pragma unroll
      for (int off = 16; off > 0; off >>= 1) v += __shfl_xor(v, off, 32);
      if (t == 0) *out_loss = (v / 31.0f) / (mean * mean + 1e-9f);
    }
  }
}

// ---------------- fused expert GEMM: 64 tokens x 1 expert per block ----------------
// YB=1: bf16 gather from xb, slot-addressed (contiguous) ybuf output.
// YB=0 (fallback): fp32 gather, atomic out.
template <int YB>
__global__ __launch_bounds__(256, 4) void k_expert(
    const float* __restrict__ x, const unsigned short* __restrict__ xb,
    const unsigned short* __restrict__ w1t, const unsigned short* __restrict__ w2t,
    const float* __restrict__ b1, const float* __restrict__ b2,
    const int* __restrict__ offsets, const int* __restrict__ counts,
    const int* __restrict__ perm, const float* __restrict__ gatev,
    unsigned short* __restrict__ ybuf, float* __restrict__ out) {
  __shared__ __align__(16) unsigned char smem[32768];   // xa: c 0..15; ha: c 0..31 (aliased)

  // XCD-affinity swizzle (2080 = 8*260, bijective)
  int bid = (int)(blockIdx.x & 7) * 260 + (int)(blockIdx.x >> 3);
  int slot0 = bid * 64;
  if (slot0 >= offsets[NE]) return;
  int e = 0;
#pragma unroll
  for (int i = 1; i < NE; ++i)
    if (slot0 >= offsets[i]) e = i;
  int cnt = counts[e];
  int local0 = slot0 - offsets[e];
  int nvalid = min(64, cnt - local0);

  int t = threadIdx.x;
  int w = t >> 6;
  int l = t & 63;
  int quad = l >> 4;
  int l15 = l & 15;

  int pvl = 0;
  float gvl = 0.f;
  if (YB) {
    uint4 v[4];
    if (l < nvalid) {
      pvl = perm[slot0 + l];
      gvl = gatev[slot0 + l];
      const uint4* rowp = (const uint4*)(xb + (size_t)pvl * DIM);
#pragma unroll
      for (int cc = 0; cc < 4; ++cc) v[cc] = rowp[w * 4 + cc];
    } else {
#pragma unroll
      for (int cc = 0; cc < 4; ++cc) { v[cc].x = 0u; v[cc].y = 0u; v[cc].z = 0u; v[cc].w = 0u; }
    }
#pragma unroll
    for (int cc = 0; cc < 4; ++cc)
      *(uint4*)(smem + LDSA(w * 4 + cc, l, 0)) = v[cc];
  } else {
    unsigned pk[16];
    if (l < nvalid) {
      pvl = perm[slot0 + l];
      gvl = gatev[slot0 + l];
      const float* src = x + (size_t)pvl * DIM + w * 32;
#pragma unroll
      for (int q = 0; q < 8; ++q) {
        float4 vv = ((const float4*)src)[q];
        pk[q * 2 + 0] = (unsigned)f2bf(vv.x) | ((unsigned)f2bf(vv.y) << 16);
        pk[q * 2 + 1] = (unsigned)f2bf(vv.z) | ((unsigned)f2bf(vv.w) << 16);
      }
    } else {
#pragma unroll
      for (int q = 0; q < 16; ++q) pk[q] = 0u;
    }
#pragma unroll
    for (int cc = 0; cc < 4; ++cc) {
      uint4 u;
      u.x = pk[cc * 4 + 0]; u.y = pk[cc * 4 + 1]; u.z = pk[cc * 4 + 2]; u.w = pk[cc * 4 + 3];
      *(uint4*)(smem + LDSA(w * 4 + cc, l, 0)) = u;
    }
  }

  const unsigned short* w1e = w1t + (size_t)e * DIM * HID;
  bf16x8 w1f[4][4];
#pragma unroll
  for (int kc = 0; kc < 4; ++kc)
#pragma unroll
    for (int jt = 0; jt < 4; ++jt)
      w1f[kc][jt] = *(const bf16x8*)(w1e + kc * 8192 + (w * 64 + jt * 16 + l15) * 32 + quad * 8);

  __syncthreads();   // (1) xa staged

  f32x4 acc[4][4];
#pragma unroll
  for (int a = 0; a < 4; ++a)
#pragma unroll
    for (int bb = 0; bb < 4; ++bb) {
      f32x4 z = {0.f, 0.f, 0.f, 0.f};
      acc[a][bb] = z;
    }
#pragma unroll
  for (int kc = 0; kc < 4; ++kc) {
    bf16x8 af[4];
#pragma unroll
    for (int rt = 0; rt < 4; ++rt)
      af[rt] = *(const bf16x8*)(smem + LDSA(kc * 4 + quad, rt * 16 + l15, 0));
#pragma unroll
    for (int rt = 0; rt < 4; ++rt)
#pragma unroll
      for (int jt = 0; jt < 4; ++jt)
        acc[rt][jt] = __builtin_amdgcn_mfma_f32_16x16x32_bf16(af[rt], w1f[kc][jt], acc[rt][jt], 0, 0, 0);
  }

  const unsigned short* w2e = w2t + (size_t)e * HID * DIM;
  bf16x8 w2f[8][2];
#pragma unroll
  for (int hc = 0; hc < 8; ++hc)
#pragma unroll
    for (int jt = 0; jt < 2; ++jt)
      w2f[hc][jt] = *(const bf16x8*)(w2e + hc * 4096 + (w * 32 + jt * 16 + l15) * 32 + quad * 8);

  __syncthreads();   // (2) all xa reads done; ha may overwrite

  // GEMM1 epilogue: lane's 4 jt-values are h = w*64 + 4*l15 + {0..3} -> one b64 write
  {
    float4 b1v = *(const float4*)(b1 + e * HID + w * 64 + 4 * l15);
    int c = w * 8 + (l15 >> 1);
    int byte = (l15 & 1) * 8;
#pragma unroll
    for (int rt = 0; rt < 4; ++rt) {
#pragma unroll
      for (int r = 0; r < 4; ++r) {
        int tokrow = rt * 16 + quad * 4 + r;
        float v0 = acc[rt][0][r] + b1v.x; v0 = v0 > 0.f ? v0 : 0.f;
        float v1 = acc[rt][1][r] + b1v.y; v1 = v1 > 0.f ? v1 : 0.f;
        float v2 = acc[rt][2][r] + b1v.z; v2 = v2 > 0.f ? v2 : 0.f;
        float v3 = acc[rt][3][r] + b1v.w; v3 = v3 > 0.f ? v3 : 0.f;
        uint2 u;
        u.x = (unsigned)f2bf(v0) | ((unsigned)f2bf(v1) << 16);
        u.y = (unsigned)f2bf(v2) | ((unsigned)f2bf(v3) << 16);
        *(uint2*)(smem + LDSA(c, tokrow, byte)) = u;
      }
    }
  }
  __syncthreads();   // (3) ha ready

  f32x4 accc[4][2];
#pragma unroll
  for (int a = 0; a < 4; ++a)
#pragma unroll
    for (int bb = 0; bb < 2; ++bb) {
      f32x4 z = {0.f, 0.f, 0.f, 0.f};
      accc[a][bb] = z;
    }
#pragma unroll
  for (int hc = 0; hc < 8; ++hc) {
    bf16x8 ah[4];
#pragma unroll
    for (int rt = 0; rt < 4; ++rt)
      ah[rt] = *(const bf16x8*)(smem + LDSA(hc * 4 + quad, rt * 16 + l15, 0));
#pragma unroll
    for (int rt = 0; rt < 4; ++rt)
#pragma unroll
      for (int jt = 0; jt < 2; ++jt)
        accc[rt][jt] = __builtin_amdgcn_mfma_f32_16x16x32_bf16(ah[rt], w2f[hc][jt], accc[rt][jt], 0, 0, 0);
  }

  // GEMM2 epilogue: lane's 2 jt-values are d = w*32 + 2*l15 + {0,1} -> one 4B store.
  // Slot-addressed ybuf: block writes rows slot0..slot0+63 (contiguous stream).
  int dbase = w * 32;
  float2 b2v = *(const float2*)(b2 + e * DIM + dbase + 2 * l15);
#pragma unroll
  for (int rt = 0; rt < 4; ++rt) {
#pragma unroll
    for (int r = 0; r < 4; ++r) {
      int tokrow = rt * 16 + quad * 4 + r;
      int pv = __shfl(pvl, tokrow);     // all lanes participate
      float g = __shfl(gvl, tokrow);
      if (tokrow < nvalid) {
        float y0 = g * (accc[rt][0][r] + b2v.x);
        float y1 = g * (accc[rt][1][r] + b2v.y);
        if (YB) {
          unsigned pack = (unsigned)f2bf(y0) | ((unsigned)f2bf(y1) << 16);
          *(unsigned*)(ybuf + (size_t)(slot0 + tokrow) * DIM + dbase + 2 * l15) = pack;
        } else {
          float* orow = out + (size_t)pv * DIM + dbase + 2 * l15;
          atomicAdd(&orow[0], y0);
          atomicAdd(&orow[1], y1);
        }
      }
    }
  }
}

// ---------------- combine: out[n] = ybuf[inv[2n]] + ybuf[inv[2n+1]] ----------------
__global__ __launch_bounds__(256) void k_combine(const unsigned short* __restrict__ ybuf,
                                                 const int* __restrict__ inv,
                                                 float* __restrict__ out) {
  int t = threadIdx.x;
  int n = blockIdx.x * 16 + (t >> 4);
  int lane = t & 15;
  int2 iv = ((const int2*)inv)[n];
  uint4 a = *((const uint4*)(ybuf + (size_t)iv.x * DIM) + lane);
  uint4 b = *((const uint4*)(ybuf + (size_t)iv.y * DIM) + lane);
  unsigned av[4] = {a.x, a.y, a.z, a.w}, bv[4] = {b.x, b.y, b.z, b.w};
  float r[8];
#pragma unroll
  for (int q = 0; q < 4; ++q) {
    r[q * 2 + 0] = bf2f(av[q] & 0xffffu) + bf2f(bv[q] & 0xffffu);
    r[q * 2 + 1] = bf2f(av[q] >> 16) + bf2f(bv[q] >> 16);
  }
  float* orow = out + (size_t)n * DIM + lane * 8;
  float4 w0 = {r[0], r[1], r[2], r[3]}, w1 = {r[4], r[5], r[6], r[7]};
  ((float4*)orow)[0] = w0;
  ((float4*)orow)[1] = w1;
}

extern "C" void kernel_launch(void* const* d_in, const int* in_sizes, int n_in,
                              void* d_out, int out_size, void* d_ws, size_t ws_size,
                              hipStream_t stream) {
  const float* x  = (const float*)d_in[0];
  const float* W1 = (const float*)d_in[1];
  const float* b1 = (const float*)d_in[2];
  const float* W2 = (const float*)d_in[3];
  const float* b2 = (const float*)d_in[4];
  const float* Wr = (const float*)d_in[5];
  const float* br = (const float*)d_in[6];
  float* out = (float*)d_out;

  char* ws = (char*)d_ws;
  int*   counts   = (int*)(ws + 0);         // 32 i
  int*   offsets  = (int*)(ws + 128);       // 33 i
  int*   top_idx  = (int*)(ws + 1024);      // 131072 i -> 525312
  float* top_val  = (float*)(ws + 525312);  // 131072 f -> 1049600
  int*   perm     = (int*)(ws + 1049600);   // 133120 i -> 1582080
  float* gatev    = (float*)(ws + 1582080); // 133120 f -> 2114560
  int*   inv      = (int*)(ws + 2114560);   // 131072 i -> 2638848
  int*   histbuf  = (int*)(ws + 2638848);   // 512*32 i -> 2704384
  float* impbuf   = (float*)(ws + 2704384); // 512*32 f -> 2769920
  unsigned short* w1t = (unsigned short*)(ws + 2769920);  // 2 MB -> 4867072
  unsigned short* w2t = (unsigned short*)(ws + 4867072);  // 2 MB -> 6964224
  unsigned short* ybuf = (unsigned short*)(ws + 6964224); // 33554432 -> 40518656
  const size_t NEEDED = 40518656;
  bool use_ybuf = ws_size >= NEEDED;

  // bf16 copy of x in the head of `out` (16.8 MB): written by k_front's router
  // blocks, consumed by k_expert<1>, fully overwritten by k_combine afterwards.
  unsigned short* xb = (unsigned short*)out;

  if (use_ybuf) {
    hipLaunchKernelGGL(k_front, dim3(1024), dim3(256), 0, stream, x, W1, W2, Wr, br,
                       top_idx, top_val, xb, w1t, w2t, histbuf, impbuf);
    hipLaunchKernelGGL(k_scatter2, dim3(512), dim3(256), 0, stream, top_idx, top_val,
                       histbuf, impbuf, perm, gatev, inv, offsets, counts,
                       out + (size_t)N_TOK * DIM);
    hipLaunchKernelGGL((k_expert<1>), dim3(2080), dim3(256), 0, stream, x, xb, w1t, w2t,
                       b1, b2, offsets, counts, perm, gatev, ybuf, out);
    hipLaunchKernelGGL(k_combine, dim3(4096), dim3(256), 0, stream, ybuf, inv, out);
  } else {
    hipLaunchKernelGGL(k_front, dim3(1024), dim3(256), 0, stream, x, W1, W2, Wr, br,
                       top_idx, top_val, xb, w1t, w2t, histbuf, impbuf);
    hipLaunchKernelGGL(k_scatter2, dim3(512), dim3(256), 0, stream, top_idx, top_val,
                       histbuf, impbuf, perm, gatev, inv, offsets, counts,
                       out + (size_t)N_TOK * DIM);
    hipLaunchKernelGGL(k_zero_out, dim3(4096), dim3(256), 0, stream, out);
    hipLaunchKernelGGL((k_expert<0>), dim3(2080), dim3(256), 0, stream, x,
                       (const unsigned short*)0, w1t, w2t, b1, b2, offsets, counts,
                       perm, gatev, (unsigned short*)0, out);
  }
}

// Round 5
// 177.963 us; speedup vs baseline: 1.2235x; 1.1812x over previous
//
#include <hip/hip_runtime.h>
#include <hip/hip_bf16.h>
#include <cstdint>
#include <cstddef>

#define N_TOK 65536
#define DIM 128
#define HID 256
#define NE 32
#define TOPK 2

typedef __bf16 bf16x8 __attribute__((ext_vector_type(8)));
typedef float f32x4 __attribute__((ext_vector_type(4)));
typedef unsigned uint4v __attribute__((ext_vector_type(4)));

// LDS address with XOR swizzle: inject c's low 2 bits into bank bits 5-6.
#define LDSA(c, row, byte) ((((c) * 1024 + (row) * 16 + (byte))) ^ ((((c) & 3) << 5)))

__device__ __forceinline__ unsigned short f2bf(float f) {
  unsigned u = __builtin_bit_cast(unsigned, f);
  u += 0x7fffu + ((u >> 16) & 1u);   // round-to-nearest-even
  return (unsigned short)(u >> 16);
}
__device__ __forceinline__ float bf2f(unsigned s) {
  return __builtin_bit_cast(float, s << 16);
}
// truncation split: f = hi + lo + O(2^-14 |f|); packs two values' shorts into one uint.
__device__ __forceinline__ uint2 split2(float f0, float f1) {
  unsigned u0 = __builtin_bit_cast(unsigned, f0);
  unsigned u1 = __builtin_bit_cast(unsigned, f1);
  unsigned hi = (u0 >> 16) | (u1 & 0xffff0000u);
  float r0 = f0 - __builtin_bit_cast(float, u0 & 0xffff0000u);
  float r1 = f1 - __builtin_bit_cast(float, u1 & 0xffff0000u);
  unsigned lo = (__builtin_bit_cast(unsigned, r0) >> 16) |
                (__builtin_bit_cast(unsigned, r1) & 0xffff0000u);
  uint2 ret; ret.x = hi; ret.y = lo;
  return ret;
}

// ---------------- fallback-only: zero out ----------------
__global__ void k_zero_out(float* __restrict__ out) {
  int t = blockIdx.x * 256 + threadIdx.x;
  float4 z = make_float4(0.f, 0.f, 0.f, 0.f);
  float4* o4 = (float4*)out;
  o4[t] = z;
  o4[t + 1048576] = z;
}

// ---------------- k_front: router (+inline fp64 fix, hist, xb) + weight transpose ----------------
// blocks 0..511:    router, 128 tokens each. Builds Wr MFMA fragments directly from Wr.
// blocks 512..1023: W1/W2 bf16 transpose with fragment-col remap:
//   w1t fragment col (jt,l15) within 64-group <-> actual h = base + 4*l15 + jt
//   w2t fragment col (jt,l15) within 32-group <-> actual d = base + 2*l15 + jt
__global__ __launch_bounds__(256, 2) void k_front(
    const float* __restrict__ x, const float* __restrict__ W1,
    const float* __restrict__ W2, const float* __restrict__ Wr,
    const float* __restrict__ br,
    int* __restrict__ top_idx, float* __restrict__ top_val,
    unsigned short* __restrict__ xb,
    unsigned short* __restrict__ w1t, unsigned short* __restrict__ w2t,
    int* __restrict__ histbuf, float* __restrict__ impbuf) {
  int b = blockIdx.x;
  int t = threadIdx.x;

  if (b >= 512) {
    // ---------- weight transpose ----------
    int bb = b - 512;
    const float* in;
    unsigned short* outp;
    int K, r0, c0;
    bool isW1;
    if (bb < 256) {
      int e = bb >> 3, tt = bb & 7;
      in = W1 + (size_t)e * DIM * HID;   // [d][h] 128x256
      outp = w1t + (size_t)e * DIM * HID;
      K = HID;
      r0 = (tt >> 2) * 64; c0 = (tt & 3) * 64;
      isW1 = true;
    } else {
      bb -= 256;
      int e = bb >> 3, tt = bb & 7;
      in = W2 + (size_t)e * HID * DIM;   // [h][d] 256x128
      outp = w2t + (size_t)e * HID * DIM;
      K = DIM;
      r0 = (tt >> 1) * 64; c0 = (tt & 1) * 64;
      isW1 = false;
    }
    __shared__ float tile[64][65];
    int r = t >> 2, cs = (t & 3) * 16;
    const float* src = in + (size_t)(r0 + r) * K + c0 + cs;
#pragma unroll
    for (int j = 0; j < 4; ++j) {
      float4 v = *(const float4*)(src + j * 4);
      tile[r][cs + j * 4 + 0] = v.x;
      tile[r][cs + j * 4 + 1] = v.y;
      tile[r][cs + j * 4 + 2] = v.z;
      tile[r][cs + j * 4 + 3] = v.w;
    }
    __syncthreads();
#pragma unroll
    for (int p = 0; p < 2; ++p) {
      int orow = p * 32 + (t >> 3);
      int oc8 = (t & 7) * 8;
      int rr = r0 + oc8;
      unsigned pk[4];
#pragma unroll
      for (int q = 0; q < 4; ++q) {
        unsigned lo = f2bf(tile[oc8 + 2 * q][orow]);
        unsigned hi = f2bf(tile[oc8 + 2 * q + 1][orow]);
        pk[q] = lo | (hi << 16);
      }
      uint4 u;
      u.x = pk[0]; u.y = pk[1]; u.z = pk[2]; u.w = pk[3];
      int h = c0 + orow;
      int hp = isW1 ? ((h & ~63) | ((h & 3) << 4) | ((h & 63) >> 2))
                    : ((h & ~31) | ((h & 1) << 4) | ((h & 31) >> 1));
      size_t addr = (size_t)(rr >> 5) * (K * 32) + (size_t)hp * 32 + (rr & 31);
      *(uint4*)(outp + addr) = u;
    }
    return;
  }

  // ---------- router ----------
  __shared__ int hc[NE];
  __shared__ float hf[NE];
  __shared__ int slist[128];
  __shared__ int scount;
  if (t < NE) { hc[t] = 0; hf[t] = 0.f; }
  if (t == 0) scount = 0;
  __syncthreads();

  int w = t >> 6, l = t & 63, quad = l >> 4, l15 = l & 15;
  int tok0 = b * 128 + w * 32;

  // Build B fragments (hi/lo split) directly from Wr (L1/L2-hot 16 KB table)
  bf16x8 bfr[2][2][4];
#pragma unroll
  for (int nt = 0; nt < 2; ++nt)
#pragma unroll
    for (int kc = 0; kc < 4; ++kc) {
      unsigned hiw[4], low[4];
#pragma unroll
      for (int jp = 0; jp < 4; ++jp) {
        int k0 = kc * 32 + quad * 8 + jp * 2;
        int e = nt * 16 + l15;
        float w0 = Wr[k0 * NE + e];
        float w1v = Wr[(k0 + 1) * NE + e];
        uint2 s = split2(w0, w1v);
        hiw[jp] = s.x; low[jp] = s.y;
      }
      uint4v h4, l4;
      h4[0] = hiw[0]; h4[1] = hiw[1]; h4[2] = hiw[2]; h4[3] = hiw[3];
      l4[0] = low[0]; l4[1] = low[1]; l4[2] = low[2]; l4[3] = low[3];
      bfr[0][nt][kc] = __builtin_bit_cast(bf16x8, h4);
      bfr[1][nt][kc] = __builtin_bit_cast(bf16x8, l4);
    }

  f32x4 acc[2][2];
#pragma unroll
  for (int a = 0; a < 2; ++a)
#pragma unroll
    for (int bb = 0; bb < 2; ++bb) {
      f32x4 z = {0.f, 0.f, 0.f, 0.f};
      acc[a][bb] = z;
    }

#pragma unroll
  for (int mt = 0; mt < 2; ++mt) {
    const float* xp = x + (size_t)(tok0 + mt * 16 + l15) * DIM + quad * 8;
    float4 va[4][2];
#pragma unroll
    for (int kc = 0; kc < 4; ++kc) {
      const float4* p = (const float4*)(xp + kc * 32);
      va[kc][0] = p[0];
      va[kc][1] = p[1];
    }
    // bf16 row-major copy of x for k_expert's gather
    unsigned short* xrow = xb + (size_t)(tok0 + mt * 16 + l15) * DIM + quad * 8;
#pragma unroll
    for (int kc = 0; kc < 4; ++kc) {
      uint4 u;
      u.x = (unsigned)f2bf(va[kc][0].x) | ((unsigned)f2bf(va[kc][0].y) << 16);
      u.y = (unsigned)f2bf(va[kc][0].z) | ((unsigned)f2bf(va[kc][0].w) << 16);
      u.z = (unsigned)f2bf(va[kc][1].x) | ((unsigned)f2bf(va[kc][1].y) << 16);
      u.w = (unsigned)f2bf(va[kc][1].z) | ((unsigned)f2bf(va[kc][1].w) << 16);
      *(uint4*)(xrow + kc * 32) = u;
    }
#pragma unroll
    for (int kc = 0; kc < 4; ++kc) {
      uint2 s0 = split2(va[kc][0].x, va[kc][0].y);
      uint2 s1 = split2(va[kc][0].z, va[kc][0].w);
      uint2 s2 = split2(va[kc][1].x, va[kc][1].y);
      uint2 s3 = split2(va[kc][1].z, va[kc][1].w);
      uint4v hu, lu;
      hu[0] = s0.x; lu[0] = s0.y;
      hu[1] = s1.x; lu[1] = s1.y;
      hu[2] = s2.x; lu[2] = s2.y;
      hu[3] = s3.x; lu[3] = s3.y;
      bf16x8 ahi = __builtin_bit_cast(bf16x8, hu);
      bf16x8 alo = __builtin_bit_cast(bf16x8, lu);
#pragma unroll
      for (int nt = 0; nt < 2; ++nt) {
        acc[mt][nt] = __builtin_amdgcn_mfma_f32_16x16x32_bf16(ahi, bfr[0][nt][kc], acc[mt][nt], 0, 0, 0);
        acc[mt][nt] = __builtin_amdgcn_mfma_f32_16x16x32_bf16(ahi, bfr[1][nt][kc], acc[mt][nt], 0, 0, 0);
        acc[mt][nt] = __builtin_amdgcn_mfma_f32_16x16x32_bf16(alo, bfr[0][nt][kc], acc[mt][nt], 0, 0, 0);
      }
    }
  }

  float brv0 = br[l15], brv1 = br[16 + l15];
  const float NINF = -3.0e38f;
#pragma unroll
  for (int mt = 0; mt < 2; ++mt) {
#pragma unroll
    for (int r = 0; r < 4; ++r) {
      float c0 = acc[mt][0][r] + brv0;
      float c1 = acc[mt][1][r] + brv1;
      // pass 1: max with lowest-index tiebreak
      float va = (c0 >= c1) ? c0 : c1;
      int ia = (c0 >= c1) ? l15 : 16 + l15;
#pragma unroll
      for (int off = 1; off < 16; off <<= 1) {
        float ov = __shfl_xor(va, off);
        int oi = __shfl_xor(ia, off);
        if (ov > va || (ov == va && oi < ia)) { va = ov; ia = oi; }
      }
      float v1 = va; int i1 = ia;
      // pass 2
      float d0 = (i1 == l15) ? NINF : c0;
      float d1 = (i1 == 16 + l15) ? NINF : c1;
      float vb = (d0 >= d1) ? d0 : d1;
      int ib = (d0 >= d1) ? l15 : 16 + l15;
#pragma unroll
      for (int off = 1; off < 16; off <<= 1) {
        float ov = __shfl_xor(vb, off);
        int oi = __shfl_xor(ib, off);
        if (ov > vb || (ov == vb && oi < ib)) { vb = ov; ib = oi; }
      }
      float v2 = vb; int i2 = ib;
      // pass 3: third-largest (suspect detection)
      float e0 = (i1 == l15 || i2 == l15) ? NINF : c0;
      float e1 = (i1 == 16 + l15 || i2 == 16 + l15) ? NINF : c1;
      float vc = (e0 >= e1) ? e0 : e1;
#pragma unroll
      for (int off = 1; off < 16; off <<= 1) {
        float ov = __shfl_xor(vc, off);
        vc = (ov > vc) ? ov : vc;
      }
      // softmax denominator
      float s = __expf(c0 - v1) + __expf(c1 - v1);
#pragma unroll
      for (int off = 1; off < 16; off <<= 1) s += __shfl_xor(s, off);
      if (l15 == 0) {
        int n = tok0 + mt * 16 + quad * 4 + r;
        int2 ti; ti.x = i1; ti.y = i2;
        float2 tv; tv.x = 1.0f / s; tv.y = __expf(v2 - v1) / s;
        ((int2*)top_idx)[n] = ti;
        ((float2*)top_val)[n] = tv;
        atomicAdd(&hc[i1], 1);
        atomicAdd(&hc[i2], 1);
        atomicAdd(&hf[i1], tv.x);
        atomicAdd(&hf[i2], tv.y);
        if (v2 - vc < 2e-3f) {
          int si = atomicAdd(&scount, 1);
          if (si < 128) slist[si] = n;
        }
      }
    }
  }
  __syncthreads();

  // ---------- inline fp64 re-resolution of this block's near-tie tokens ----------
  int sc = scount;
  for (int s = (t >> 5); s < sc; s += 8) {
    int lt = t & 31;
    int n = slist[s];
    const float* xr = x + (size_t)n * DIM;
    double a = 0.0;
#pragma unroll 8
    for (int d = 0; d < DIM; ++d) a = fma((double)xr[d], (double)Wr[d * NE + lt], a);
    double lv = a + (double)br[lt];

    double v1 = lv; int i1 = lt;
#pragma unroll
    for (int off = 16; off > 0; off >>= 1) {
      double ov = __shfl_xor(v1, off, 32);
      int oi = __shfl_xor(i1, off, 32);
      if (ov > v1 || (ov == v1 && oi < i1)) { v1 = ov; i1 = oi; }
    }
    double lv2 = (lt == i1) ? -1.0e300 : lv;
    double v2 = lv2; int i2 = lt;
#pragma unroll
    for (int off = 16; off > 0; off >>= 1) {
      double ov = __shfl_xor(v2, off, 32);
      int oi = __shfl_xor(i2, off, 32);
      if (ov > v2 || (ov == v2 && oi < i2)) { v2 = ov; i2 = oi; }
    }
    float p = expf((float)(lv - v1));
    float ssum = p;
#pragma unroll
    for (int off = 16; off > 0; off >>= 1) ssum += __shfl_xor(ssum, off, 32);
    if (lt == 0) {
      int o1 = top_idx[n * 2 + 0];
      int o2 = top_idx[n * 2 + 1];
      float w1v = top_val[n * 2 + 0];
      float w2v = top_val[n * 2 + 1];
      float nv1 = 1.0f / ssum;
      float nv2 = expf((float)(v2 - v1)) / ssum;
      atomicAdd(&hc[o1], -1); atomicAdd(&hc[o2], -1);
      atomicAdd(&hc[i1], 1);  atomicAdd(&hc[i2], 1);
      atomicAdd(&hf[o1], -w1v); atomicAdd(&hf[o2], -w2v);
      atomicAdd(&hf[i1], nv1);  atomicAdd(&hf[i2], nv2);
      top_idx[n * 2 + 0] = i1;
      top_idx[n * 2 + 1] = i2;
      top_val[n * 2 + 0] = nv1;
      top_val[n * 2 + 1] = nv2;
    }
  }
  __syncthreads();
  if (t < NE) {
    histbuf[b * NE + t] = hc[t];
    impbuf[b * NE + t] = hf[t];
  }
}

// ---------------- k_scatter2: deterministic scatter + offsets/counts/loss + inv map ----------------
// perm[pos] = token; inv[token*2+slot] = pos (for combine's gather)
__global__ __launch_bounds__(256) void k_scatter2(
    const int* __restrict__ top_idx, const float* __restrict__ top_val,
    const int* __restrict__ histbuf, const float* __restrict__ impbuf,
    int* __restrict__ perm, float* __restrict__ gatev, int* __restrict__ inv,
    int* __restrict__ offsets, int* __restrict__ counts, float* __restrict__ out_loss) {
  __shared__ int pf[8][32], pb[8][32];
  __shared__ int offs[NE], pref[NE], h2[NE];
  int b = blockIdx.x, t = threadIdx.x;
  if (t < NE) h2[t] = 0;
  int g = t >> 5, e = t & 31;
  int sf = 0, sb = 0;
  for (int j = 0; j < 64; ++j) {
    int bb = g * 64 + j;
    int v = histbuf[bb * NE + e];
    sf += v;
    sb += (bb < b) ? v : 0;
  }
  pf[g][e] = sf;
  pb[g][e] = sb;
  __syncthreads();
  if (t < 32) {
    int T = 0, P = 0;
#pragma unroll
    for (int g2 = 0; g2 < 8; ++g2) { T += pf[g2][t]; P += pb[g2][t]; }
    int pc = (T + 63) & ~63;
    int scn = pc;
#pragma unroll
    for (int off = 1; off < 32; off <<= 1) {
      int ov = __shfl_up(scn, off, 32);
      if (t >= off) scn += ov;
    }
    offs[t] = scn - pc;
    pref[t] = P;
    if (b == 0) {
      offsets[t] = scn - pc;
      counts[t] = T;
      if (t == 31) offsets[NE] = scn;
    }
  }
  __syncthreads();
  if (t < 128) {
    int n = b * 128 + t;
    int2 ti = ((const int2*)top_idx)[n];
    float2 tv = ((const float2*)top_val)[n];
    int r0 = atomicAdd(&h2[ti.x], 1);
    int r1 = atomicAdd(&h2[ti.y], 1);
    int p0 = offs[ti.x] + pref[ti.x] + r0;
    int p1 = offs[ti.y] + pref[ti.y] + r1;
    perm[p0] = n;
    gatev[p0] = tv.x;
    perm[p1] = n;
    gatev[p1] = tv.y;
    int2 iv; iv.x = p0; iv.y = p1;
    ((int2*)inv)[n] = iv;
  }
  if (b == 0) {
    __shared__ float pfi[8][32];
    float s2 = 0.f;
    for (int j = 0; j < 64; ++j) s2 += impbuf[(g * 64 + j) * NE + e];
    pfi[g][e] = s2;
    __syncthreads();
    if (t < 32) {
      float imp = 0.f;
#pragma unroll
      for (int g2 = 0; g2 < 8; ++g2) imp += pfi[g2][t];
      float ssum = imp;
#pragma unroll
      for (int off = 16; off > 0; off >>= 1) ssum += __shfl_xor(ssum, off, 32);
      float mean = ssum / 32.0f;
      float dlt = imp - mean;
      float v = dlt * dlt;
#pragma unroll
      for (int off = 16; off > 0; off >>= 1) v += __shfl_xor(v, off, 32);
      if (t == 0) *out_loss = (v / 31.0f) / (mean * mean + 1e-9f);
    }
  }
}

// ---------------- fused expert GEMM: 64 tokens x 1 expert per block ----------------
// YB=1: bf16 gather from xb, slot-addressed (contiguous) ybuf output.
// YB=0 (fallback): fp32 gather, atomic out.
// __launch_bounds__(256,3): ~168 VGPR budget -> NO SPILL (rounds 3/4's (256,4)
// capped at 64 VGPR and spilled ~128 MB of scratch traffic per dispatch).
template <int YB>
__global__ __launch_bounds__(256, 3) void k_expert(
    const float* __restrict__ x, const unsigned short* __restrict__ xb,
    const unsigned short* __restrict__ w1t, const unsigned short* __restrict__ w2t,
    const float* __restrict__ b1, const float* __restrict__ b2,
    const int* __restrict__ offsets, const int* __restrict__ counts,
    const int* __restrict__ perm, const float* __restrict__ gatev,
    unsigned short* __restrict__ ybuf, float* __restrict__ out) {
  __shared__ __align__(16) unsigned char smem[32768];   // xa: c 0..15; ha: c 0..31 (aliased)

  // XCD-affinity swizzle (2080 = 8*260, bijective)
  int bid = (int)(blockIdx.x & 7) * 260 + (int)(blockIdx.x >> 3);
  int slot0 = bid * 64;
  if (slot0 >= offsets[NE]) return;
  int e = 0;
#pragma unroll
  for (int i = 1; i < NE; ++i)
    if (slot0 >= offsets[i]) e = i;
  int cnt = counts[e];
  int local0 = slot0 - offsets[e];
  int nvalid = min(64, cnt - local0);

  int t = threadIdx.x;
  int w = t >> 6;
  int l = t & 63;
  int quad = l >> 4;
  int l15 = l & 15;

  int pvl = 0;
  float gvl = 0.f;
  if (YB) {
    uint4 v[4];
    if (l < nvalid) {
      pvl = perm[slot0 + l];
      gvl = gatev[slot0 + l];
      const uint4* rowp = (const uint4*)(xb + (size_t)pvl * DIM);
#pragma unroll
      for (int cc = 0; cc < 4; ++cc) v[cc] = rowp[w * 4 + cc];
    } else {
#pragma unroll
      for (int cc = 0; cc < 4; ++cc) { v[cc].x = 0u; v[cc].y = 0u; v[cc].z = 0u; v[cc].w = 0u; }
    }
#pragma unroll
    for (int cc = 0; cc < 4; ++cc)
      *(uint4*)(smem + LDSA(w * 4 + cc, l, 0)) = v[cc];
  } else {
    unsigned pk[16];
    if (l < nvalid) {
      pvl = perm[slot0 + l];
      gvl = gatev[slot0 + l];
      const float* src = x + (size_t)pvl * DIM + w * 32;
#pragma unroll
      for (int q = 0; q < 8; ++q) {
        float4 vv = ((const float4*)src)[q];
        pk[q * 2 + 0] = (unsigned)f2bf(vv.x) | ((unsigned)f2bf(vv.y) << 16);
        pk[q * 2 + 1] = (unsigned)f2bf(vv.z) | ((unsigned)f2bf(vv.w) << 16);
      }
    } else {
#pragma unroll
      for (int q = 0; q < 16; ++q) pk[q] = 0u;
    }
#pragma unroll
    for (int cc = 0; cc < 4; ++cc) {
      uint4 u;
      u.x = pk[cc * 4 + 0]; u.y = pk[cc * 4 + 1]; u.z = pk[cc * 4 + 2]; u.w = pk[cc * 4 + 3];
      *(uint4*)(smem + LDSA(w * 4 + cc, l, 0)) = u;
    }
  }

  const unsigned short* w1e = w1t + (size_t)e * DIM * HID;
  bf16x8 w1f[4][4];
#pragma unroll
  for (int kc = 0; kc < 4; ++kc)
#pragma unroll
    for (int jt = 0; jt < 4; ++jt)
      w1f[kc][jt] = *(const bf16x8*)(w1e + kc * 8192 + (w * 64 + jt * 16 + l15) * 32 + quad * 8);

  __syncthreads();   // (1) xa staged

  f32x4 acc[4][4];
#pragma unroll
  for (int a = 0; a < 4; ++a)
#pragma unroll
    for (int bb = 0; bb < 4; ++bb) {
      f32x4 z = {0.f, 0.f, 0.f, 0.f};
      acc[a][bb] = z;
    }
#pragma unroll
  for (int kc = 0; kc < 4; ++kc) {
    bf16x8 af[4];
#pragma unroll
    for (int rt = 0; rt < 4; ++rt)
      af[rt] = *(const bf16x8*)(smem + LDSA(kc * 4 + quad, rt * 16 + l15, 0));
#pragma unroll
    for (int rt = 0; rt < 4; ++rt)
#pragma unroll
      for (int jt = 0; jt < 4; ++jt)
        acc[rt][jt] = __builtin_amdgcn_mfma_f32_16x16x32_bf16(af[rt], w1f[kc][jt], acc[rt][jt], 0, 0, 0);
  }

  const unsigned short* w2e = w2t + (size_t)e * HID * DIM;
  bf16x8 w2f[8][2];
#pragma unroll
  for (int hc = 0; hc < 8; ++hc)
#pragma unroll
    for (int jt = 0; jt < 2; ++jt)
      w2f[hc][jt] = *(const bf16x8*)(w2e + hc * 4096 + (w * 32 + jt * 16 + l15) * 32 + quad * 8);

  __syncthreads();   // (2) all xa reads done; ha may overwrite

  // GEMM1 epilogue: lane's 4 jt-values are h = w*64 + 4*l15 + {0..3} -> one b64 write
  {
    float4 b1v = *(const float4*)(b1 + e * HID + w * 64 + 4 * l15);
    int c = w * 8 + (l15 >> 1);
    int byte = (l15 & 1) * 8;
#pragma unroll
    for (int rt = 0; rt < 4; ++rt) {
#pragma unroll
      for (int r = 0; r < 4; ++r) {
        int tokrow = rt * 16 + quad * 4 + r;
        float v0 = acc[rt][0][r] + b1v.x; v0 = v0 > 0.f ? v0 : 0.f;
        float v1 = acc[rt][1][r] + b1v.y; v1 = v1 > 0.f ? v1 : 0.f;
        float v2 = acc[rt][2][r] + b1v.z; v2 = v2 > 0.f ? v2 : 0.f;
        float v3 = acc[rt][3][r] + b1v.w; v3 = v3 > 0.f ? v3 : 0.f;
        uint2 u;
        u.x = (unsigned)f2bf(v0) | ((unsigned)f2bf(v1) << 16);
        u.y = (unsigned)f2bf(v2) | ((unsigned)f2bf(v3) << 16);
        *(uint2*)(smem + LDSA(c, tokrow, byte)) = u;
      }
    }
  }
  __syncthreads();   // (3) ha ready

  f32x4 accc[4][2];
#pragma unroll
  for (int a = 0; a < 4; ++a)
#pragma unroll
    for (int bb = 0; bb < 2; ++bb) {
      f32x4 z = {0.f, 0.f, 0.f, 0.f};
      accc[a][bb] = z;
    }
#pragma unroll
  for (int hc = 0; hc < 8; ++hc) {
    bf16x8 ah[4];
#pragma unroll
    for (int rt = 0; rt < 4; ++rt)
      ah[rt] = *(const bf16x8*)(smem + LDSA(hc * 4 + quad, rt * 16 + l15, 0));
#pragma unroll
    for (int rt = 0; rt < 4; ++rt)
#pragma unroll
      for (int jt = 0; jt < 2; ++jt)
        accc[rt][jt] = __builtin_amdgcn_mfma_f32_16x16x32_bf16(ah[rt], w2f[hc][jt], accc[rt][jt], 0, 0, 0);
  }

  // GEMM2 epilogue: lane's 2 jt-values are d = w*32 + 2*l15 + {0,1} -> one 4B store.
  // Slot-addressed ybuf: block writes rows slot0..slot0+63 (contiguous stream).
  int dbase = w * 32;
  float2 b2v = *(const float2*)(b2 + e * DIM + dbase + 2 * l15);
#pragma unroll
  for (int rt = 0; rt < 4; ++rt) {
#pragma unroll
    for (int r = 0; r < 4; ++r) {
      int tokrow = rt * 16 + quad * 4 + r;
      int pv = __shfl(pvl, tokrow);     // all lanes participate
      float g = __shfl(gvl, tokrow);
      if (tokrow < nvalid) {
        float y0 = g * (accc[rt][0][r] + b2v.x);
        float y1 = g * (accc[rt][1][r] + b2v.y);
        if (YB) {
          unsigned pack = (unsigned)f2bf(y0) | ((unsigned)f2bf(y1) << 16);
          *(unsigned*)(ybuf + (size_t)(slot0 + tokrow) * DIM + dbase + 2 * l15) = pack;
        } else {
          float* orow = out + (size_t)pv * DIM + dbase + 2 * l15;
          atomicAdd(&orow[0], y0);
          atomicAdd(&orow[1], y1);
        }
      }
    }
  }
}

// ---------------- combine: out[n] = ybuf[inv[2n]] + ybuf[inv[2n+1]] ----------------
__global__ __launch_bounds__(256) void k_combine(const unsigned short* __restrict__ ybuf,
                                                 const int* __restrict__ inv,
                                                 float* __restrict__ out) {
  int t = threadIdx.x;
  int n = blockIdx.x * 16 + (t >> 4);
  int lane = t & 15;
  int2 iv = ((const int2*)inv)[n];
  uint4 a = *((const uint4*)(ybuf + (size_t)iv.x * DIM) + lane);
  uint4 b = *((const uint4*)(ybuf + (size_t)iv.y * DIM) + lane);
  unsigned av[4] = {a.x, a.y, a.z, a.w}, bv[4] = {b.x, b.y, b.z, b.w};
  float r[8];
#pragma unroll
  for (int q = 0; q < 4; ++q) {
    r[q * 2 + 0] = bf2f(av[q] & 0xffffu) + bf2f(bv[q] & 0xffffu);
    r[q * 2 + 1] = bf2f(av[q] >> 16) + bf2f(bv[q] >> 16);
  }
  float* orow = out + (size_t)n * DIM + lane * 8;
  float4 w0 = {r[0], r[1], r[2], r[3]}, w1 = {r[4], r[5], r[6], r[7]};
  ((float4*)orow)[0] = w0;
  ((float4*)orow)[1] = w1;
}

extern "C" void kernel_launch(void* const* d_in, const int* in_sizes, int n_in,
                              void* d_out, int out_size, void* d_ws, size_t ws_size,
                              hipStream_t stream) {
  const float* x  = (const float*)d_in[0];
  const float* W1 = (const float*)d_in[1];
  const float* b1 = (const float*)d_in[2];
  const float* W2 = (const float*)d_in[3];
  const float* b2 = (const float*)d_in[4];
  const float* Wr = (const float*)d_in[5];
  const float* br = (const float*)d_in[6];
  float* out = (float*)d_out;

  char* ws = (char*)d_ws;
  int*   counts   = (int*)(ws + 0);         // 32 i
  int*   offsets  = (int*)(ws + 128);       // 33 i
  int*   top_idx  = (int*)(ws + 1024);      // 131072 i -> 525312
  float* top_val  = (float*)(ws + 525312);  // 131072 f -> 1049600
  int*   perm     = (int*)(ws + 1049600);   // 133120 i -> 1582080
  float* gatev    = (float*)(ws + 1582080); // 133120 f -> 2114560
  int*   inv      = (int*)(ws + 2114560);   // 131072 i -> 2638848
  int*   histbuf  = (int*)(ws + 2638848);   // 512*32 i -> 2704384
  float* impbuf   = (float*)(ws + 2704384); // 512*32 f -> 2769920
  unsigned short* w1t = (unsigned short*)(ws + 2769920);  // 2 MB -> 4867072
  unsigned short* w2t = (unsigned short*)(ws + 4867072);  // 2 MB -> 6964224
  unsigned short* ybuf = (unsigned short*)(ws + 6964224); // 33554432 -> 40518656
  const size_t NEEDED = 40518656;
  bool use_ybuf = ws_size >= NEEDED;

  // bf16 copy of x in the head of `out` (16.8 MB): written by k_front's router
  // blocks, consumed by k_expert<1>, fully overwritten by k_combine afterwards.
  unsigned short* xb = (unsigned short*)out;

  if (use_ybuf) {
    hipLaunchKernelGGL(k_front, dim3(1024), dim3(256), 0, stream, x, W1, W2, Wr, br,
                       top_idx, top_val, xb, w1t, w2t, histbuf, impbuf);
    hipLaunchKernelGGL(k_scatter2, dim3(512), dim3(256), 0, stream, top_idx, top_val,
                       histbuf, impbuf, perm, gatev, inv, offsets, counts,
                       out + (size_t)N_TOK * DIM);
    hipLaunchKernelGGL((k_expert<1>), dim3(2080), dim3(256), 0, stream, x, xb, w1t, w2t,
                       b1, b2, offsets, counts, perm, gatev, ybuf, out);
    hipLaunchKernelGGL(k_combine, dim3(4096), dim3(256), 0, stream, ybuf, inv, out);
  } else {
    hipLaunchKernelGGL(k_front, dim3(1024), dim3(256), 0, stream, x, W1, W2, Wr, br,
                       top_idx, top_val, xb, w1t, w2t, histbuf, impbuf);
    hipLaunchKernelGGL(k_scatter2, dim3(512), dim3(256), 0, stream, top_idx, top_val,
                       histbuf, impbuf, perm, gatev, inv, offsets, counts,
                       out + (size_t)N_TOK * DIM);
    hipLaunchKernelGGL(k_zero_out, dim3(4096), dim3(256), 0, stream, out);
    hipLaunchKernelGGL((k_expert<0>), dim3(2080), dim3(256), 0, stream, x,
                       (const unsigned short*)0, w1t, w2t, b1, b2, offsets, counts,
                       perm, gatev, (unsigned short*)0, out);
  }
}